// Round 6
// baseline (1453.667 us; speedup 1.0000x reference)
//
#include <hip/hip_runtime.h>
#include <cstdint>
#include <cstddef>

#define TN   8192
#define DD   512
#define NPER 4
#define KNN  5

typedef _Float16 f16x8 __attribute__((ext_vector_type(8)));
typedef _Float16 f16x4 __attribute__((ext_vector_type(4)));
typedef float    f32x4 __attribute__((ext_vector_type(4)));

// key = sq_row - 2 * acc / 4096^2  ->  fmaf(acc, -2^-23, sq_row)
#define KSCALE (-1.1920928955078125e-07f)

// ---------------------------------------------------------------------------
// Sorted-5 insert, ascending by (val, idx) — matches stable argsort ties.
// ---------------------------------------------------------------------------
__device__ __forceinline__ void ins5(float v, int ix, float tv[KNN], int ti[KNN]) {
  if (v < tv[4] || (v == tv[4] && ix < ti[4])) {
    tv[4] = v; ti[4] = ix;
#pragma unroll
    for (int s = 4; s > 0; --s) {
      bool sw = (tv[s] < tv[s-1]) || (tv[s] == tv[s-1] && ti[s] < ti[s-1]);
      float nhi = sw ? tv[s-1] : tv[s];
      float nlo = sw ? tv[s]   : tv[s-1];
      int   ihi = sw ? ti[s-1] : ti[s];
      int   ilo = sw ? ti[s]   : ti[s-1];
      tv[s] = nhi; tv[s-1] = nlo;
      ti[s] = ihi; ti[s-1] = ilo;
    }
  }
}

__device__ __forceinline__ void gll16(const void* g, void* l) {
  __builtin_amdgcn_global_load_lds(
      (const __attribute__((address_space(1))) void*)g,
      (__attribute__((address_space(3))) void*)l, 16, 0, 0);
}

// ---------------------------------------------------------------------------
// Kernel 0: fused hi/lo fp16 split of X*4096 AND rowsq. One wave per row.
// ---------------------------------------------------------------------------
__global__ void prep_sq(const float* __restrict__ X,
                        _Float16* __restrict__ H, _Float16* __restrict__ L,
                        float* __restrict__ rowsq) {
  const int row  = (int)blockIdx.x * 4 + ((int)threadIdx.x >> 6);
  const int lane = (int)threadIdx.x & 63;
  const float4* xr = (const float4*)(X + (size_t)row * DD);
  const float4 a = xr[lane];
  const float4 b = xr[lane + 64];
  float xa[4] = {a.x, a.y, a.z, a.w};
  float xb[4] = {b.x, b.y, b.z, b.w};
  f16x4 ha, la, hb, lb;
#pragma unroll
  for (int j = 0; j < 4; ++j) {
    float s = xa[j] * 4096.f;
    _Float16 h = (_Float16)s;
    ha[j] = h; la[j] = (_Float16)(s - (float)h);
    s = xb[j] * 4096.f;
    h = (_Float16)s;
    hb[j] = h; lb[j] = (_Float16)(s - (float)h);
  }
  f16x4* Hr = (f16x4*)(H + (size_t)row * DD);
  f16x4* Lr = (f16x4*)(L + (size_t)row * DD);
  Hr[lane] = ha; Hr[lane + 64] = hb;
  Lr[lane] = la; Lr[lane + 64] = lb;

  float s = a.x*a.x + a.y*a.y + a.z*a.z + a.w*a.w
          + b.x*b.x + b.y*b.y + b.z*b.z + b.w*b.w;
#pragma unroll
  for (int off = 32; off >= 1; off >>= 1) s += __shfl_down(s, off, 64);
  if (lane == 0) rowsq[row] = s;
}

// ---------------------------------------------------------------------------
// Kernel 2: fp16 split-MFMA GEMM (K = 3*512: HH + HL + LH), fused column-mode
// top-5. 256x256 block tile (4x FLOP per barrier vs R5's 128x128), 512 thr =
// 8 waves, wave tile 64x128: acc[4][8] = 128 AGPR, af[4]+bf[8] = 48 VGPR.
// __launch_bounds__(512,2) -> 256-unified-reg cap (demand ~216, no spill).
// LDS: 2 bufs x (A 16KB + B 16KB) = 64 KB, linear dest via global_load_lds.
// T2 swizzle (verified 0-conflict R4/R5): LDS row r holds global k-slot
// (q ^ ((r>>1)&3)) at 16B-slot q (pre-swizzled global source); read addr
// row*64 + (lgrp ^ ((lidx>>1)&3))*16.
// C layout (m89): col = lane&15, row = 4*(lane>>4) + reg.
// Partials: one top5 per (col, 256-row block rb, wr) -> [8192][128][10B].
// ---------------------------------------------------------------------------
__launch_bounds__(512, 2)
__global__ void gemm_mfma(const _Float16* __restrict__ H, const _Float16* __restrict__ L,
                          const float* __restrict__ rowsq, float* __restrict__ partials) {
  __shared__ __align__(16) char smem[65536];
  const int tid  = (int)threadIdx.x;
  const int lane = tid & 63;
  const int w    = tid >> 6;                  // wave 0..7
  const int wr   = w >> 1, wc = w & 1;        // 4x2 wave grid (64x128 each)
  // XCD-aware swizzle (T1): nwg=1024 % 8 == 0 -> bijective
  const int bid  = ((int)blockIdx.x & 7) * 128 + ((int)blockIdx.x >> 3);
  const int rb   = bid & 31;                  // 32 row-blocks of 256
  const int cb   = bid >> 5;                  // 32 col-blocks of 256
  const int row0 = rb * 256;
  const int jb   = cb * 256;
  const int lgrp = lane >> 4;                 // k-group / C row-group
  const int lidx = lane & 15;                 // A-row / B-col within frag
  const int srw  = lane >> 2;                 // staging row 0..15
  const int swk  = ((lane & 3) ^ ((srw >> 1) & 3)) * 8;   // swizzled src k (f16)
  const int swr  = (lgrp ^ ((lidx >> 1) & 3)) * 16;       // swizzled read bytes

  // hoisted per-thread staging offsets (f16 elements); +8192 = +16 rows
  const size_t aoff = (size_t)(row0 + 32*w + srw) * DD + swk;
  const size_t boff = (size_t)(jb   + 32*w + srw) * DD + swk;
  char* const abase = smem + 2048*w;          // + buf*32768
  char* const bbase = smem + 16384 + 2048*w;

#define STAGE(buf, ksv) do {                                                    \
    const int seg_ = (ksv) >> 4;                                                \
    const int kko_ = ((ksv) & 15) * 32;                                         \
    const _Float16* pa_ = (seg_ == 2) ? L : H;                                  \
    const _Float16* pb_ = (seg_ == 1) ? L : H;                                  \
    gll16(pa_ + aoff + kko_,        abase + (buf)*32768);                       \
    gll16(pa_ + aoff + 8192 + kko_, abase + (buf)*32768 + 1024);                \
    gll16(pb_ + boff + kko_,        bbase + (buf)*32768);                       \
    gll16(pb_ + boff + 8192 + kko_, bbase + (buf)*32768 + 1024);                \
  } while (0)

#define COMPUTE(buf) do {                                                       \
    const char* Ab_ = smem + (buf)*32768;                                       \
    const char* Bb_ = Ab_ + 16384;                                              \
    f16x8 af[4], bf[8];                                                         \
    _Pragma("unroll")                                                           \
    for (int t = 0; t < 4; ++t)                                                 \
      af[t] = *(const f16x8*)(Ab_ + wr*4096 + t*1024 + lidx*64 + swr);          \
    _Pragma("unroll")                                                           \
    for (int u = 0; u < 8; ++u)                                                 \
      bf[u] = *(const f16x8*)(Bb_ + wc*8192 + u*1024 + lidx*64 + swr);          \
    _Pragma("unroll")                                                           \
    for (int t = 0; t < 4; ++t)                                                 \
      _Pragma("unroll")                                                         \
      for (int u = 0; u < 8; ++u)                                               \
        acc[t][u] = __builtin_amdgcn_mfma_f32_16x16x32_f16(af[t], bf[u],        \
                                                           acc[t][u], 0, 0, 0); \
  } while (0)

  f32x4 acc[4][8] = {};

  STAGE(0, 0);
  __syncthreads();

  for (int ks = 0; ks < 48; ks += 2) {        // K = 1536 in chunks of 32
    STAGE(1, ks + 1);                         // prefetch odd chunk -> buf1
    COMPUTE(0);
    __syncthreads();                          // buf0 consumed + buf1 staged
    if (ks + 2 < 48) STAGE(0, ks + 2);        // prefetch next even -> buf0
    COMPUTE(1);
    __syncthreads();
  }

  // ---- fused selection epilogue (column-mode; wave reduces its 64 rows) ----
  float4 sqr[4];
#pragma unroll
  for (int t = 0; t < 4; ++t)
    sqr[t] = *(const float4*)(rowsq + row0 + wr*64 + t*16 + lgrp*4);

#pragma unroll
  for (int cf = 0; cf < 8; ++cf) {
    const int jc = jb + wc*128 + cf*16 + lidx;  // this lane's center column
    float tv[KNN]; int ti[KNN];
#pragma unroll
    for (int s = 0; s < KNN; ++s) { tv[s] = 3.4e38f; ti[s] = 0x3fffffff; }
#pragma unroll
    for (int t = 0; t < 4; ++t) {
      const int rbase = row0 + wr*64 + t*16 + lgrp*4;
      float key;
      key = fmaf(acc[t][cf][0], KSCALE, sqr[t].x); if (rbase+0 != jc) ins5(key, rbase+0, tv, ti);
      key = fmaf(acc[t][cf][1], KSCALE, sqr[t].y); if (rbase+1 != jc) ins5(key, rbase+1, tv, ti);
      key = fmaf(acc[t][cf][2], KSCALE, sqr[t].z); if (rbase+2 != jc) ins5(key, rbase+2, tv, ti);
      key = fmaf(acc[t][cf][3], KSCALE, sqr[t].w); if (rbase+3 != jc) ins5(key, rbase+3, tv, ti);
    }
    // merge the 4 lanes (same col, different row-groups): d = 16, 32
#pragma unroll
    for (int d = 16; d <= 32; d <<= 1) {
      float ov[KNN]; int oi[KNN];
#pragma unroll
      for (int s = 0; s < KNN; ++s) {
        ov[s] = __shfl_xor(tv[s], d, 64);
        oi[s] = __shfl_xor(ti[s], d, 64);
      }
#pragma unroll
      for (int s = 0; s < KNN; ++s) ins5(ov[s], oi[s], tv, ti);
    }
    if (lane < 16) {                          // one writer per column
      float* pw = partials + ((size_t)jc * 128 + rb*4 + wr) * 10;
#pragma unroll
      for (int s = 0; s < KNN; ++s) { pw[2*s] = tv[s]; ((int*)pw)[2*s+1] = ti[s]; }
    }
  }
#undef STAGE
#undef COMPUTE
}

// ---------------------------------------------------------------------------
// Kernel 3: fold 128 partial top-5 lists per column -> nn[T][5] (sorted).
// One wave per column, two partials per lane.
// ---------------------------------------------------------------------------
__global__ void merge_nn(const float* __restrict__ parts, int* __restrict__ nn) {
  const int j    = (int)blockIdx.x * 4 + ((int)threadIdx.x >> 6);
  const int lane = (int)threadIdx.x & 63;
  float tv[KNN]; int ti[KNN];
#pragma unroll
  for (int s = 0; s < KNN; ++s) { tv[s] = 3.4e38f; ti[s] = 0x3fffffff; }
  const float* p0 = parts + ((size_t)j * 128 + lane) * 10;
  const float* p1 = parts + ((size_t)j * 128 + lane + 64) * 10;
#pragma unroll
  for (int s = 0; s < KNN; ++s) ins5(p0[2*s], ((const int*)p0)[2*s+1], tv, ti);
#pragma unroll
  for (int s = 0; s < KNN; ++s) ins5(p1[2*s], ((const int*)p1)[2*s+1], tv, ti);
#pragma unroll
  for (int d = 1; d < 64; d <<= 1) {
    float ov[KNN]; int oi[KNN];
#pragma unroll
    for (int s = 0; s < KNN; ++s) {
      ov[s] = __shfl_xor(tv[s], d, 64);
      oi[s] = __shfl_xor(ti[s], d, 64);
    }
#pragma unroll
    for (int s = 0; s < KNN; ++s) ins5(ov[s], oi[s], tv, ti);
  }
  if (lane == 0) {
#pragma unroll
    for (int s = 0; s < KNN; ++s) nn[j*KNN + s] = ti[s];
  }
}

// ---------------------------------------------------------------------------
// Kernel 4: synthesis  out[i*4+p] = x_i + g * (x_nn - x_i)
// ---------------------------------------------------------------------------
__global__ void synth_kernel(const float* __restrict__ X, const int* __restrict__ nn,
                             const float* __restrict__ gaps, const int* __restrict__ choice,
                             float* __restrict__ out) {
  const float4* X4 = (const float4*)X;
  float4* O4 = (float4*)out;
  const int base = (int)blockIdx.x * 256 + (int)threadIdx.x;
#pragma unroll
  for (int it = 0; it < 8; ++it) {
    const int f    = base + it * (2048 * 256);
    const int orow = f >> 7;
    const int d4   = f & 127;
    const int i    = orow >> 2;
    const int ch   = choice[orow];
    const int nr   = nn[i * KNN + ch];
    const float g  = gaps[orow];
    const float4 xi = X4[(size_t)i  * 128 + d4];
    const float4 xn = X4[(size_t)nr * 128 + d4];
    float4 r;
    r.x = fmaf(g, xn.x - xi.x, xi.x);
    r.y = fmaf(g, xn.y - xi.y, xi.y);
    r.z = fmaf(g, xn.z - xi.z, xi.z);
    r.w = fmaf(g, xn.w - xi.w, xi.w);
    O4[(size_t)orow * 128 + d4] = r;
  }
}

// ---------------------------------------------------------------------------
// d_out (64 MB) doubles as scratch: H[8MB] | L[8MB] | partials[42MB] — synth
// fully rewrites d_out last. d_ws holds rowsq + nn (~200 KB).
// ---------------------------------------------------------------------------
extern "C" void kernel_launch(void* const* d_in, const int* in_sizes, int n_in,
                              void* d_out, int out_size, void* d_ws, size_t ws_size,
                              hipStream_t stream) {
  const float* X      = (const float*)d_in[0];
  const float* gaps   = (const float*)d_in[1];
  const int*   choice = (const int*)  d_in[2];
  float* out = (float*)d_out;

  _Float16* Hbuf  = (_Float16*)d_out;                       // [0, 8M)
  _Float16* Lbuf  = (_Float16*)((char*)d_out + 8388608);    // [8M, 16M)
  float*    parts = (float*)((char*)d_out + 16777216);      // [16M, 58M)

  float* rowsq = (float*)d_ws;                              // 32 KB
  int*   nn    = (int*)((char*)d_ws + TN * 4);              // 160 KB

  prep_sq     <<<2048, 256, 0, stream>>>(X, Hbuf, Lbuf, rowsq);
  gemm_mfma   <<<1024, 512, 0, stream>>>(Hbuf, Lbuf, rowsq, parts);
  merge_nn    <<<2048, 256, 0, stream>>>(parts, nn);
  synth_kernel<<<2048, 256, 0, stream>>>(X, nn, gaps, choice, out);
}

// Round 7
// 1435.547 us; speedup vs baseline: 1.0126x; 1.0126x over previous
//
#include <hip/hip_runtime.h>
#include <cstdint>
#include <cstddef>

#define TN   8192
#define DD   512
#define NPER 4
#define KNN  5

typedef _Float16 f16x8 __attribute__((ext_vector_type(8)));
typedef _Float16 f16x4 __attribute__((ext_vector_type(4)));
typedef float    f32x4 __attribute__((ext_vector_type(4)));

// key = sq_row - 2 * acc / 4096^2  ->  fmaf(acc, -2^-23, sq_row)
#define KSCALE (-1.1920928955078125e-07f)

// ---------------------------------------------------------------------------
__device__ __forceinline__ void ins5(float v, int ix, float tv[KNN], int ti[KNN]) {
  if (v < tv[4] || (v == tv[4] && ix < ti[4])) {
    tv[4] = v; ti[4] = ix;
#pragma unroll
    for (int s = 4; s > 0; --s) {
      bool sw = (tv[s] < tv[s-1]) || (tv[s] == tv[s-1] && ti[s] < ti[s-1]);
      float nhi = sw ? tv[s-1] : tv[s];
      float nlo = sw ? tv[s]   : tv[s-1];
      int   ihi = sw ? ti[s-1] : ti[s];
      int   ilo = sw ? ti[s]   : ti[s-1];
      tv[s] = nhi; tv[s-1] = nlo;
      ti[s] = ihi; ti[s-1] = ilo;
    }
  }
}

__device__ __forceinline__ void gll16(const void* g, void* l) {
  __builtin_amdgcn_global_load_lds(
      (const __attribute__((address_space(1))) void*)g,
      (__attribute__((address_space(3))) void*)l, 16, 0, 0);
}

// ---------------------------------------------------------------------------
// Kernel 0: fused hi/lo fp16 split of X*4096 AND rowsq. One wave per row.
// ---------------------------------------------------------------------------
__global__ void prep_sq(const float* __restrict__ X,
                        _Float16* __restrict__ H, _Float16* __restrict__ L,
                        float* __restrict__ rowsq) {
  const int row  = (int)blockIdx.x * 4 + ((int)threadIdx.x >> 6);
  const int lane = (int)threadIdx.x & 63;
  const float4* xr = (const float4*)(X + (size_t)row * DD);
  const float4 a = xr[lane];
  const float4 b = xr[lane + 64];
  float xa[4] = {a.x, a.y, a.z, a.w};
  float xb[4] = {b.x, b.y, b.z, b.w};
  f16x4 ha, la, hb, lb;
#pragma unroll
  for (int j = 0; j < 4; ++j) {
    float s = xa[j] * 4096.f;
    _Float16 h = (_Float16)s;
    ha[j] = h; la[j] = (_Float16)(s - (float)h);
    s = xb[j] * 4096.f;
    h = (_Float16)s;
    hb[j] = h; lb[j] = (_Float16)(s - (float)h);
  }
  f16x4* Hr = (f16x4*)(H + (size_t)row * DD);
  f16x4* Lr = (f16x4*)(L + (size_t)row * DD);
  Hr[lane] = ha; Hr[lane + 64] = hb;
  Lr[lane] = la; Lr[lane + 64] = lb;

  float s = a.x*a.x + a.y*a.y + a.z*a.z + a.w*a.w
          + b.x*b.x + b.y*b.y + b.z*b.z + b.w*b.w;
#pragma unroll
  for (int off = 32; off >= 1; off >>= 1) s += __shfl_down(s, off, 64);
  if (lane == 0) rowsq[row] = s;
}

// ---------------------------------------------------------------------------
// Kernel 2: fp16 split-MFMA GEMM (K = 3*512: HH + HL + LH), fused column-mode
// top-5, 256x256 tile, 8 waves, wave tile 64x128 (acc[4][8] = 128 AGPR).
// SCHEDULE (T4): 3-deep LDS pipeline (3 x 32 KB dynamic LDS), counted
// s_waitcnt vmcnt(8) + RAW s_barrier (no vmcnt(0) drain in the main loop —
// HIP's __syncthreads always drains, hence R5/R6's 18K-cyc phases).
// Per K-step: wait vmcnt(8) [stage ks done, ks+1/ks+2 in flight] -> barrier
// -> ds_read frags + MFMA (setprio, T5) -> barrier -> re-stage buf for ks+3.
// Race-safety: all 12 ds_reads are consumed by MFMAs before barrier-B
// (compiler lgkmcnt), so the post-barrier DMA re-stage cannot collide.
// T2 swizzle (verified R4-R6): LDS row r holds global k-slot (q^((r>>1)&3))
// at 16B-slot q (pre-swizzled global source); read row*64+(lgrp^((lidx>>1)&3))*16.
// C layout (m89): col = lane&15, row = 4*(lane>>4) + reg.
// ---------------------------------------------------------------------------
#define VMWAIT_(n) asm volatile("s_waitcnt vmcnt(" #n ")" ::: "memory")
#define VMWAIT(n)  VMWAIT_(n)

__launch_bounds__(512, 1)
__global__ void gemm_mfma(const _Float16* __restrict__ H, const _Float16* __restrict__ L,
                          const float* __restrict__ rowsq, float* __restrict__ partials) {
  extern __shared__ __align__(16) char smem[];   // 3 * 32768 = 98304 B
  const int tid  = (int)threadIdx.x;
  const int lane = tid & 63;
  const int w    = tid >> 6;                  // wave 0..7
  const int wr   = w >> 1, wc = w & 1;        // wave tile 64 rows x 128 cols
  // XCD-aware swizzle (T1): nwg=1024 % 8 == 0 -> bijective
  const int bid  = ((int)blockIdx.x & 7) * 128 + ((int)blockIdx.x >> 3);
  const int rb   = bid & 31;                  // 32 row-blocks of 256
  const int cb   = bid >> 5;                  // 32 col-blocks of 256
  const int row0 = rb * 256;
  const int jb   = cb * 256;
  const int lgrp = lane >> 4;
  const int lidx = lane & 15;
  const int srw  = lane >> 2;                 // staging row 0..15
  const int swk  = ((lane & 3) ^ ((srw >> 1) & 3)) * 8;   // swizzled src k (f16)
  const int swr  = (lgrp ^ ((lidx >> 1) & 3)) * 16;       // swizzled read bytes

  // hoisted per-lane staging offsets (f16 elements); +8192 elems = +16 rows
  const size_t aoff = (size_t)(row0 + 32*w + srw) * DD + swk;
  const size_t boff = (size_t)(jb   + 32*w + srw) * DD + swk;

#define STAGE(cur, ksv) do {                                                    \
    const int seg_ = (ksv) >> 4;                                                \
    const int kko_ = ((ksv) & 15) * 32;                                         \
    const _Float16* pa_ = (seg_ == 2) ? L : H;                                  \
    const _Float16* pb_ = (seg_ == 1) ? L : H;                                  \
    char* ab_ = smem + (cur)*32768 + 2048*w;                                    \
    char* bb_ = smem + (cur)*32768 + 16384 + 2048*w;                            \
    gll16(pa_ + aoff + kko_,        ab_);                                       \
    gll16(pa_ + aoff + 8192 + kko_, ab_ + 1024);                                \
    gll16(pb_ + boff + kko_,        bb_);                                       \
    gll16(pb_ + boff + 8192 + kko_, bb_ + 1024);                                \
  } while (0)

#define COMPUTE(cur) do {                                                       \
    const char* Ab_ = smem + (cur)*32768;                                       \
    const char* Bb_ = Ab_ + 16384;                                              \
    f16x8 af[4], bf[8];                                                         \
    _Pragma("unroll")                                                           \
    for (int t = 0; t < 4; ++t)                                                 \
      af[t] = *(const f16x8*)(Ab_ + wr*4096 + t*1024 + lidx*64 + swr);          \
    _Pragma("unroll")                                                           \
    for (int u = 0; u < 8; ++u)                                                 \
      bf[u] = *(const f16x8*)(Bb_ + wc*8192 + u*1024 + lidx*64 + swr);          \
    __builtin_amdgcn_s_setprio(1);                                              \
    _Pragma("unroll")                                                           \
    for (int t = 0; t < 4; ++t)                                                 \
      _Pragma("unroll")                                                         \
      for (int u = 0; u < 8; ++u)                                               \
        acc[t][u] = __builtin_amdgcn_mfma_f32_16x16x32_f16(af[t], bf[u],        \
                                                           acc[t][u], 0, 0, 0); \
    __builtin_amdgcn_s_setprio(0);                                              \
  } while (0)

#define BODY(cur, ksv, W, DOSTAGE) do {                                         \
    VMWAIT(W);                                                                  \
    __builtin_amdgcn_s_barrier();                                               \
    __builtin_amdgcn_sched_barrier(0);                                          \
    COMPUTE(cur);                                                               \
    __builtin_amdgcn_s_barrier();                                               \
    if (DOSTAGE) STAGE(cur, (ksv) + 3);                                         \
  } while (0)

  f32x4 acc[4][8] = {};

  STAGE(0, 0);
  STAGE(1, 1);
  STAGE(2, 2);

  int ks = 0;
  for (int g = 0; g < 15; ++g) {              // ks = 0..44, all stage ks+3<=47
    BODY(0, ks,     8, true);
    BODY(1, ks + 1, 8, true);
    BODY(2, ks + 2, 8, true);
    ks += 3;
  }
  BODY(0, 45, 8, false);                      // 45,46,47 outstanding -> retire 45
  BODY(1, 46, 4, false);                      // 46,47 outstanding -> retire 46
  BODY(2, 47, 0, false);                      // drain

  // ---- fused selection epilogue (column-mode; wave reduces its 64 rows) ----
  float4 sqr[4];
#pragma unroll
  for (int t = 0; t < 4; ++t)
    sqr[t] = *(const float4*)(rowsq + row0 + wr*64 + t*16 + lgrp*4);

#pragma unroll
  for (int cf = 0; cf < 8; ++cf) {
    const int jc = jb + wc*128 + cf*16 + lidx;  // this lane's center column
    float tv[KNN]; int ti[KNN];
#pragma unroll
    for (int s = 0; s < KNN; ++s) { tv[s] = 3.4e38f; ti[s] = 0x3fffffff; }
#pragma unroll
    for (int t = 0; t < 4; ++t) {
      const int rbase = row0 + wr*64 + t*16 + lgrp*4;
      float key;
      key = fmaf(acc[t][cf][0], KSCALE, sqr[t].x); if (rbase+0 != jc) ins5(key, rbase+0, tv, ti);
      key = fmaf(acc[t][cf][1], KSCALE, sqr[t].y); if (rbase+1 != jc) ins5(key, rbase+1, tv, ti);
      key = fmaf(acc[t][cf][2], KSCALE, sqr[t].z); if (rbase+2 != jc) ins5(key, rbase+2, tv, ti);
      key = fmaf(acc[t][cf][3], KSCALE, sqr[t].w); if (rbase+3 != jc) ins5(key, rbase+3, tv, ti);
    }
#pragma unroll
    for (int d = 16; d <= 32; d <<= 1) {        // merge 4 lanes sharing this col
      float ov[KNN]; int oi[KNN];
#pragma unroll
      for (int s = 0; s < KNN; ++s) {
        ov[s] = __shfl_xor(tv[s], d, 64);
        oi[s] = __shfl_xor(ti[s], d, 64);
      }
#pragma unroll
      for (int s = 0; s < KNN; ++s) ins5(ov[s], oi[s], tv, ti);
    }
    if (lane < 16) {                            // one writer per column
      float* pw = partials + ((size_t)jc * 128 + rb*4 + wr) * 10;
#pragma unroll
      for (int s = 0; s < KNN; ++s) { pw[2*s] = tv[s]; ((int*)pw)[2*s+1] = ti[s]; }
    }
  }
#undef STAGE
#undef COMPUTE
#undef BODY
}

// ---------------------------------------------------------------------------
// Kernel 3: fold 128 partial top-5 lists per column -> nn[T][5] (sorted).
// ---------------------------------------------------------------------------
__global__ void merge_nn(const float* __restrict__ parts, int* __restrict__ nn) {
  const int j    = (int)blockIdx.x * 4 + ((int)threadIdx.x >> 6);
  const int lane = (int)threadIdx.x & 63;
  float tv[KNN]; int ti[KNN];
#pragma unroll
  for (int s = 0; s < KNN; ++s) { tv[s] = 3.4e38f; ti[s] = 0x3fffffff; }
  const float* p0 = parts + ((size_t)j * 128 + lane) * 10;
  const float* p1 = parts + ((size_t)j * 128 + lane + 64) * 10;
#pragma unroll
  for (int s = 0; s < KNN; ++s) ins5(p0[2*s], ((const int*)p0)[2*s+1], tv, ti);
#pragma unroll
  for (int s = 0; s < KNN; ++s) ins5(p1[2*s], ((const int*)p1)[2*s+1], tv, ti);
#pragma unroll
  for (int d = 1; d < 64; d <<= 1) {
    float ov[KNN]; int oi[KNN];
#pragma unroll
    for (int s = 0; s < KNN; ++s) {
      ov[s] = __shfl_xor(tv[s], d, 64);
      oi[s] = __shfl_xor(ti[s], d, 64);
    }
#pragma unroll
    for (int s = 0; s < KNN; ++s) ins5(ov[s], oi[s], tv, ti);
  }
  if (lane == 0) {
#pragma unroll
    for (int s = 0; s < KNN; ++s) nn[j*KNN + s] = ti[s];
  }
}

// ---------------------------------------------------------------------------
// Kernel 4: synthesis  out[i*4+p] = x_i + g * (x_nn - x_i)
// ---------------------------------------------------------------------------
__global__ void synth_kernel(const float* __restrict__ X, const int* __restrict__ nn,
                             const float* __restrict__ gaps, const int* __restrict__ choice,
                             float* __restrict__ out) {
  const float4* X4 = (const float4*)X;
  float4* O4 = (float4*)out;
  const int base = (int)blockIdx.x * 256 + (int)threadIdx.x;
#pragma unroll
  for (int it = 0; it < 8; ++it) {
    const int f    = base + it * (2048 * 256);
    const int orow = f >> 7;
    const int d4   = f & 127;
    const int i    = orow >> 2;
    const int ch   = choice[orow];
    const int nr   = nn[i * KNN + ch];
    const float g  = gaps[orow];
    const float4 xi = X4[(size_t)i  * 128 + d4];
    const float4 xn = X4[(size_t)nr * 128 + d4];
    float4 r;
    r.x = fmaf(g, xn.x - xi.x, xi.x);
    r.y = fmaf(g, xn.y - xi.y, xi.y);
    r.z = fmaf(g, xn.z - xi.z, xi.z);
    r.w = fmaf(g, xn.w - xi.w, xi.w);
    O4[(size_t)orow * 128 + d4] = r;
  }
}

// ---------------------------------------------------------------------------
// d_out (64 MB) doubles as scratch: H[8MB] | L[8MB] | partials[42MB] — synth
// fully rewrites d_out last. d_ws holds rowsq + nn (~200 KB).
// ---------------------------------------------------------------------------
extern "C" void kernel_launch(void* const* d_in, const int* in_sizes, int n_in,
                              void* d_out, int out_size, void* d_ws, size_t ws_size,
                              hipStream_t stream) {
  const float* X      = (const float*)d_in[0];
  const float* gaps   = (const float*)d_in[1];
  const int*   choice = (const int*)  d_in[2];
  float* out = (float*)d_out;

  _Float16* Hbuf  = (_Float16*)d_out;                       // [0, 8M)
  _Float16* Lbuf  = (_Float16*)((char*)d_out + 8388608);    // [8M, 16M)
  float*    parts = (float*)((char*)d_out + 16777216);      // [16M, 58M)

  float* rowsq = (float*)d_ws;                              // 32 KB
  int*   nn    = (int*)((char*)d_ws + TN * 4);              // 160 KB

  // allow 96 KB dynamic LDS (idempotent; not a stream op -> capture-safe)
  static_cast<void>(hipFuncSetAttribute((const void*)gemm_mfma,
      hipFuncAttributeMaxDynamicSharedMemorySize, 98304));

  prep_sq     <<<2048, 256, 0, stream>>>(X, Hbuf, Lbuf, rowsq);
  gemm_mfma   <<<1024, 512, 98304, stream>>>(Hbuf, Lbuf, rowsq, parts);
  merge_nn    <<<2048, 256, 0, stream>>>(parts, nn);
  synth_kernel<<<2048, 256, 0, stream>>>(X, nn, gaps, choice, out);
}

// Round 8
// 458.610 us; speedup vs baseline: 3.1697x; 3.1302x over previous
//
#include <hip/hip_runtime.h>
#include <cstdint>
#include <cstddef>

#define TN   8192
#define DD   512
#define NPER 4
#define KNN  5

typedef _Float16 f16x8 __attribute__((ext_vector_type(8)));
typedef _Float16 f16x4 __attribute__((ext_vector_type(4)));
typedef float    f32x4 __attribute__((ext_vector_type(4)));
typedef unsigned long long u64;

// key = sq_row - 2 * accHH / 4096^2  ->  fmaf(acc, -2^-23, sq_row)
#define KSCALE (-1.1920928955078125e-07f)

// ---------------------------------------------------------------------------
// Monotone pack: (f32 key, idx) -> u64 so that u64-ascending == (key, idx)
// ascending (stable-argsort ties). Handles negative keys.
// ---------------------------------------------------------------------------
__device__ __forceinline__ u64 packkey(float key, int idx) {
  unsigned int kb = __float_as_uint(key);
  kb ^= (((int)kb >> 31) | 0x80000000u);
  return ((u64)kb << 32) | (unsigned int)idx;
}

// Sorted-8 insert (ascending u64). All indices static after unroll.
__device__ __forceinline__ void ins8(u64 v, u64 tv[8]) {
  if (v < tv[7]) {
    tv[7] = v;
#pragma unroll
    for (int s = 7; s > 0; --s) {
      u64 lo = tv[s] < tv[s-1] ? tv[s] : tv[s-1];
      u64 hi = tv[s] < tv[s-1] ? tv[s-1] : tv[s];
      tv[s-1] = lo; tv[s] = hi;
    }
  }
}

__device__ __forceinline__ void gll16(const void* g, void* l) {
  __builtin_amdgcn_global_load_lds(
      (const __attribute__((address_space(1))) void*)g,
      (__attribute__((address_space(3))) void*)l, 16, 0, 0);
}

// ---------------------------------------------------------------------------
// Kernel 0: hi fp16 of X*4096 AND exact rowsq. One wave per row. (No L buffer
// needed — HH-only screen + exact refine replaces the 3-term split.)
// ---------------------------------------------------------------------------
__global__ void prep_sq(const float* __restrict__ X,
                        _Float16* __restrict__ H, float* __restrict__ rowsq) {
  const int row  = (int)blockIdx.x * 4 + ((int)threadIdx.x >> 6);
  const int lane = (int)threadIdx.x & 63;
  const float4* xr = (const float4*)(X + (size_t)row * DD);
  const float4 a = xr[lane];
  const float4 b = xr[lane + 64];
  float xa[4] = {a.x, a.y, a.z, a.w};
  float xb[4] = {b.x, b.y, b.z, b.w};
  f16x4 ha, hb;
#pragma unroll
  for (int j = 0; j < 4; ++j) {
    ha[j] = (_Float16)(xa[j] * 4096.f);
    hb[j] = (_Float16)(xb[j] * 4096.f);
  }
  f16x4* Hr = (f16x4*)(H + (size_t)row * DD);
  Hr[lane] = ha; Hr[lane + 64] = hb;

  float s = a.x*a.x + a.y*a.y + a.z*a.z + a.w*a.w
          + b.x*b.x + b.y*b.y + b.z*b.z + b.w*b.w;
#pragma unroll
  for (int off = 32; off >= 1; off >>= 1) s += __shfl_down(s, off, 64);
  if (lane == 0) rowsq[row] = s;
}

// ---------------------------------------------------------------------------
// Kernel 1: HH screening GEMM (K = 512 only) + fused column-mode top-8.
// R5's proven shell: 128x128 tile, 4 waves, wave tile 64x64 (acc 4x4 of
// 16x16x32 f16 = 64 AGPR), BK=32, LDS 2x16KB, global_load_lds w16, T2
// source-pre-swizzle (verified 0-conflict R4-R7).
// Epilogue: u64-packed (key,idx) top-8 per (col, 128-row block); wr-pair
// merged via LDS -> partials u64[8192 cols][64 rb][8].
// C layout (m89): col = lane&15, row = 4*(lane>>4) + reg.
// ---------------------------------------------------------------------------
__launch_bounds__(256, 2)
__global__ void gemm_top8(const _Float16* __restrict__ Hp,
                          const float* __restrict__ rowsq, u64* __restrict__ partials) {
  __shared__ __align__(16) char smem[32768];
  const int tid  = (int)threadIdx.x;
  const int lane = tid & 63;
  const int w    = tid >> 6;                  // wave 0..3
  const int wr   = w >> 1, wc = w & 1;        // 2x2 wave grid
  // XCD-aware swizzle (T1): nwg=4096 % 8 == 0 -> bijective
  const int bid  = ((int)blockIdx.x & 7) * 512 + ((int)blockIdx.x >> 3);
  const int rb   = bid & 63;                  // 64 row-blocks of 128
  const int cb   = bid >> 6;                  // 64 col-blocks of 128
  const int row0 = rb * 128;
  const int jb   = cb * 128;
  const int lgrp = lane >> 4;                 // k-group / C row-group
  const int lidx = lane & 15;                 // A-row / B-col within frag
  const int srw  = lane >> 2;                 // staging row 0..15
  const int swk  = ((lane & 3) ^ ((srw >> 1) & 3)) * 8;   // swizzled src k (f16)
  const int swr  = (lgrp ^ ((lidx >> 1) & 3)) * 16;       // swizzled read bytes

  const size_t aoff = (size_t)(row0 + 32*w + srw) * DD + swk;
  const size_t boff = (size_t)(jb   + 32*w + srw) * DD + swk;

#define STAGE(buf, ksv) do {                                                    \
    const int kko_ = (ksv) * 32;                                                \
    char* ab_ = smem + (buf)*16384 + 2048*w;                                    \
    char* bb_ = smem + (buf)*16384 + 8192 + 2048*w;                             \
    gll16(Hp + aoff + kko_,        ab_);                                        \
    gll16(Hp + aoff + 8192 + kko_, ab_ + 1024);                                 \
    gll16(Hp + boff + kko_,        bb_);                                        \
    gll16(Hp + boff + 8192 + kko_, bb_ + 1024);                                 \
  } while (0)

  f32x4 acc[4][4] = {};

  STAGE(0, 0);
  __syncthreads();

  for (int ks = 0; ks < 16; ++ks) {           // K = 512 in chunks of 32
    const int cur = ks & 1;
    if (ks < 15) STAGE(cur ^ 1, ks + 1);      // async prefetch into other buffer

    const char* Ab = smem + cur*16384;
    const char* Bb = Ab + 8192;
    f16x8 af[4], bf[4];
#pragma unroll
    for (int t = 0; t < 4; ++t) {
      af[t] = *(const f16x8*)(Ab + (wr*4+t)*1024 + lidx*64 + swr);
      bf[t] = *(const f16x8*)(Bb + (wc*4+t)*1024 + lidx*64 + swr);
    }
#pragma unroll
    for (int rt = 0; rt < 4; ++rt)
#pragma unroll
      for (int cf = 0; cf < 4; ++cf)
        acc[rt][cf] = __builtin_amdgcn_mfma_f32_16x16x32_f16(af[rt], bf[cf], acc[rt][cf], 0, 0, 0);

    __syncthreads();                          // cur consumed + nxt staged
  }

  // ---- fused selection epilogue: per-col u64 top-8 over this block's rows ----
  float4 sqr[4];
#pragma unroll
  for (int t = 0; t < 4; ++t)
    sqr[t] = *(const float4*)(rowsq + row0 + wr*64 + t*16 + lgrp*4);

  u64* mg = (u64*)smem;                       // 128 cols x 8 u64 = 8 KB reuse

#pragma unroll
  for (int cf = 0; cf < 4; ++cf) {
    const int jc = jb + wc*64 + cf*16 + lidx; // this lane's center column
    u64 tv[8];
#pragma unroll
    for (int s = 0; s < 8; ++s) tv[s] = ~0ull;
#pragma unroll
    for (int t = 0; t < 4; ++t) {
      const int rbase = row0 + wr*64 + t*16 + lgrp*4;
      float key;
      key = fmaf(acc[t][cf][0], KSCALE, sqr[t].x); if (rbase+0 != jc) ins8(packkey(key, rbase+0), tv);
      key = fmaf(acc[t][cf][1], KSCALE, sqr[t].y); if (rbase+1 != jc) ins8(packkey(key, rbase+1), tv);
      key = fmaf(acc[t][cf][2], KSCALE, sqr[t].z); if (rbase+2 != jc) ins8(packkey(key, rbase+2), tv);
      key = fmaf(acc[t][cf][3], KSCALE, sqr[t].w); if (rbase+3 != jc) ins8(packkey(key, rbase+3), tv);
    }
    // merge the 4 lanes (same col, different row-groups): d = 16, 32
#pragma unroll
    for (int d = 16; d <= 32; d <<= 1) {
      u64 ov[8];
#pragma unroll
      for (int s = 0; s < 8; ++s) ov[s] = __shfl_xor(tv[s], d, 64);
#pragma unroll
      for (int s = 0; s < 8; ++s) ins8(ov[s], tv);
    }
    // wr-pair merge via LDS: wr=1 publishes, wr=0 merges + stores
    if (wr == 1 && lane < 16) {
#pragma unroll
      for (int s = 0; s < 8; ++s) mg[(wc*64 + cf*16 + lidx)*8 + s] = tv[s];
    }
    __syncthreads();
    if (wr == 0 && lane < 16) {
      const u64* om = &mg[(wc*64 + cf*16 + lidx)*8];
#pragma unroll
      for (int s = 0; s < 8; ++s) ins8(om[s], tv);
      u64* pw = partials + ((size_t)jc * 64 + rb) * 8;
#pragma unroll
      for (int s = 0; s < 8; ++s) pw[s] = tv[s];
    }
    __syncthreads();                          // mg reused next cf
  }
#undef STAGE
}

// ---------------------------------------------------------------------------
// Kernel 2: fold 64 partial top-8 lists per column -> cand[T][8] (sorted u64).
// One wave per column, one partial per lane.
// ---------------------------------------------------------------------------
__global__ void merge_nn8(const u64* __restrict__ parts, u64* __restrict__ cand) {
  const int j    = (int)blockIdx.x * 4 + ((int)threadIdx.x >> 6);
  const int lane = (int)threadIdx.x & 63;
  u64 tv[8];
  const u64* p0 = parts + ((size_t)j * 64 + lane) * 8;
#pragma unroll
  for (int s = 0; s < 8; ++s) tv[s] = p0[s];
#pragma unroll
  for (int d = 1; d < 64; d <<= 1) {
    u64 ov[8];
#pragma unroll
    for (int s = 0; s < 8; ++s) ov[s] = __shfl_xor(tv[s], d, 64);
#pragma unroll
    for (int s = 0; s < 8; ++s) ins8(ov[s], tv);
  }
  if (lane == 0) {
#pragma unroll
    for (int s = 0; s < 8; ++s) cand[(size_t)j*8 + s] = tv[s];
  }
}

// ---------------------------------------------------------------------------
// Kernel 3: exact fp32 refine of the 8 candidates per center -> nn[T][5].
// One wave per center row; key = sq_cand - 2*dot(x_center, x_cand), fp32.
// ---------------------------------------------------------------------------
__global__ void refine_nn(const float* __restrict__ X, const float* __restrict__ rowsq,
                          const u64* __restrict__ cand, int* __restrict__ nn) {
  const int j    = (int)blockIdx.x * 4 + ((int)threadIdx.x >> 6);   // center
  const int lane = (int)threadIdx.x & 63;
  const float4* xj = (const float4*)(X + (size_t)j * DD);
  const float4 qa = xj[lane];
  const float4 qb = xj[lane + 64];
  u64 best[8];
#pragma unroll
  for (int s = 0; s < 8; ++s) best[s] = ~0ull;
#pragma unroll
  for (int c = 0; c < 8; ++c) {
    const int r = (int)(unsigned int)cand[(size_t)j*8 + c];
    const float4* xr_ = (const float4*)(X + (size_t)r * DD);
    const float4 a = xr_[lane];
    const float4 b = xr_[lane + 64];
    float d = a.x*qa.x + a.y*qa.y + a.z*qa.z + a.w*qa.w
            + b.x*qb.x + b.y*qb.y + b.z*qb.z + b.w*qb.w;
#pragma unroll
    for (int off = 32; off >= 1; off >>= 1) d += __shfl_xor(d, off, 64);
    const float key = fmaf(-2.f, d, rowsq[r]);
    ins8(packkey(key, r), best);              // every lane: identical result
  }
  if (lane == 0) {
#pragma unroll
    for (int s = 0; s < KNN; ++s) nn[j*KNN + s] = (int)(unsigned int)best[s];
  }
}

// ---------------------------------------------------------------------------
// Kernel 4: synthesis  out[i*4+p] = x_i + g * (x_nn - x_i)
// ---------------------------------------------------------------------------
__global__ void synth_kernel(const float* __restrict__ X, const int* __restrict__ nn,
                             const float* __restrict__ gaps, const int* __restrict__ choice,
                             float* __restrict__ out) {
  const float4* X4 = (const float4*)X;
  float4* O4 = (float4*)out;
  const int base = (int)blockIdx.x * 256 + (int)threadIdx.x;
#pragma unroll
  for (int it = 0; it < 8; ++it) {
    const int f    = base + it * (2048 * 256);
    const int orow = f >> 7;
    const int d4   = f & 127;
    const int i    = orow >> 2;
    const int ch   = choice[orow];
    const int nr   = nn[i * KNN + ch];
    const float g  = gaps[orow];
    const float4 xi = X4[(size_t)i  * 128 + d4];
    const float4 xn = X4[(size_t)nr * 128 + d4];
    float4 r;
    r.x = fmaf(g, xn.x - xi.x, xi.x);
    r.y = fmaf(g, xn.y - xi.y, xi.y);
    r.z = fmaf(g, xn.z - xi.z, xi.z);
    r.w = fmaf(g, xn.w - xi.w, xi.w);
    O4[(size_t)orow * 128 + d4] = r;
  }
}

// ---------------------------------------------------------------------------
// d_out (64 MB) scratch layout: H[8MB) | partials u64[8M..40M) | cand[40M..40.5M)
// — synth fully rewrites d_out last. d_ws: rowsq[32KB) + nn[160KB).
// ---------------------------------------------------------------------------
extern "C" void kernel_launch(void* const* d_in, const int* in_sizes, int n_in,
                              void* d_out, int out_size, void* d_ws, size_t ws_size,
                              hipStream_t stream) {
  const float* X      = (const float*)d_in[0];
  const float* gaps   = (const float*)d_in[1];
  const int*   choice = (const int*)  d_in[2];
  float* out = (float*)d_out;

  _Float16* Hbuf  = (_Float16*)d_out;                       // [0, 8M)
  u64*      parts = (u64*)((char*)d_out + 8388608);         // [8M, 40M)
  u64*      cand  = (u64*)((char*)d_out + 41943040);        // [40M, 40.5M)

  float* rowsq = (float*)d_ws;                              // 32 KB
  int*   nn    = (int*)((char*)d_ws + TN * 4);              // 160 KB

  prep_sq     <<<2048, 256, 0, stream>>>(X, Hbuf, rowsq);
  gemm_top8   <<<4096, 256, 0, stream>>>(Hbuf, rowsq, parts);
  merge_nn8   <<<2048, 256, 0, stream>>>(parts, cand);
  refine_nn   <<<2048, 256, 0, stream>>>(X, rowsq, cand, nn);
  synth_kernel<<<2048, 256, 0, stream>>>(X, nn, gaps, choice, out);
}

// Round 11
// 423.415 us; speedup vs baseline: 3.4332x; 1.0831x over previous
//
#include <hip/hip_runtime.h>
#include <cstdint>
#include <cstddef>

#define TN   8192
#define DD   512
#define NPER 4
#define KNN  5

typedef _Float16 f16x8 __attribute__((ext_vector_type(8)));
typedef _Float16 f16x4 __attribute__((ext_vector_type(4)));
typedef float    f32x4 __attribute__((ext_vector_type(4)));
typedef unsigned long long u64;

// key = sq_row - 2 * accHH / 4096^2  ->  fmaf(acc, -2^-23, sq_row)
#define KSCALE (-1.1920928955078125e-07f)

// ---------------------------------------------------------------------------
// Monotone pack: (f32 key, idx) -> u64; u64-ascending == (key, idx) ascending.
// ---------------------------------------------------------------------------
__device__ __forceinline__ u64 packkey(float key, int idx) {
  unsigned int kb = __float_as_uint(key);
  kb ^= (((int)kb >> 31) | 0x80000000u);
  return ((u64)kb << 32) | (unsigned int)idx;
}

__device__ __forceinline__ void ins8(u64 v, u64 tv[8]) {
  if (v < tv[7]) {
    tv[7] = v;
#pragma unroll
    for (int s = 7; s > 0; --s) {
      u64 lo = tv[s] < tv[s-1] ? tv[s] : tv[s-1];
      u64 hi = tv[s] < tv[s-1] ? tv[s-1] : tv[s];
      tv[s-1] = lo; tv[s] = hi;
    }
  }
}

// cap-5 sorted insert. Lost-candidate risk ~2e-5 overall (needs >=5 of a
// column's ~8 best rows inside one 16-row bin of 512 bins).
__device__ __forceinline__ void ins5u(u64 v, u64 tv[5]) {
  if (v < tv[4]) {
    tv[4] = v;
#pragma unroll
    for (int s = 4; s > 0; --s) {
      u64 lo = tv[s] < tv[s-1] ? tv[s] : tv[s-1];
      u64 hi = tv[s] < tv[s-1] ? tv[s-1] : tv[s];
      tv[s-1] = lo; tv[s] = hi;
    }
  }
}

// ---------------------------------------------------------------------------
// Kernel 0: hi fp16 of X*4096 AND exact rowsq. One wave per row.
// ---------------------------------------------------------------------------
__global__ void prep_sq(const float* __restrict__ X,
                        _Float16* __restrict__ H, float* __restrict__ rowsq) {
  const int row  = (int)blockIdx.x * 4 + ((int)threadIdx.x >> 6);
  const int lane = (int)threadIdx.x & 63;
  const float4* xr = (const float4*)(X + (size_t)row * DD);
  const float4 a = xr[lane];
  const float4 b = xr[lane + 64];
  float xa[4] = {a.x, a.y, a.z, a.w};
  float xb[4] = {b.x, b.y, b.z, b.w};
  f16x4 ha, hb;
#pragma unroll
  for (int j = 0; j < 4; ++j) {
    ha[j] = (_Float16)(xa[j] * 4096.f);
    hb[j] = (_Float16)(xb[j] * 4096.f);
  }
  f16x4* Hr = (f16x4*)(H + (size_t)row * DD);
  Hr[lane] = ha; Hr[lane + 64] = hb;

  float s = a.x*a.x + a.y*a.y + a.z*a.z + a.w*a.w
          + b.x*b.x + b.y*b.y + b.z*b.z + b.w*b.w;
#pragma unroll
  for (int off = 32; off >= 1; off >>= 1) s += __shfl_down(s, off, 64);
  if (lane == 0) rowsq[row] = s;
}

// ---------------------------------------------------------------------------
// Kernel 1: HH screening GEMM (K = 512), NO LDS in the K-loop — fragments
// loaded directly global->reg (H is 8 MB, L2/L3-resident). 4 independent
// waves (2x2 of 64x64), 2-deep register ping-pong, zero K-loop barriers.
// Fragment addressing matches the m89 layout: lane (lgrp,lidx) reads
// row/col (tile + lidx), k = ks*32 + lgrp*8 .. +7 (16B/lane; 4 lgrp lanes
// cover the row's full 64B K-chunk -> whole-line L2 requests).
// Epilogue: per-lane cap-5 over its 16 rows -> SNAPSHOT butterfly d=16,32
// (R10 BUG: d=32 exchanged t8 while mutating it; must snapshot first) ->
// wave-col top-8 -> LDS wr-pair merge (R8-proven) ->
// partials u64[8192 cols][64 rb][8]. Downstream kernels unchanged.
// launch_bounds(256,3): ~170-reg cap; demand ~160 (64 acc + 64 frag + addr)
// — (256,8) would cap at 64 and spill massively (R2/R4 failure mode).
// C layout (m89): col = lane&15, row = 4*(lane>>4) + reg.
// ---------------------------------------------------------------------------
__launch_bounds__(256, 3)
__global__ void gemm_top8(const _Float16* __restrict__ Hp,
                          const float* __restrict__ rowsq, u64* __restrict__ partials) {
  __shared__ u64 mg[128 * 8];                 // 8 KB: wr-pair merge buffer
  const int tid  = (int)threadIdx.x;
  const int lane = tid & 63;
  const int w    = tid >> 6;                  // wave 0..3
  const int wr   = w >> 1, wc = w & 1;        // 2x2 wave grid
  // XCD-aware swizzle (T1): nwg=4096 % 8 == 0 -> bijective; cb fastest so
  // consecutive bids on one XCD share the A row-panel (L2 locality).
  const int bid  = ((int)blockIdx.x & 7) * 512 + ((int)blockIdx.x >> 3);
  const int rb   = bid >> 6;                  // 64 row-blocks of 128
  const int cb   = bid & 63;                  // 64 col-blocks of 128
  const int row0 = rb * 128;
  const int jb   = cb * 128;
  const int lgrp = lane >> 4;                 // k-group / C row-group
  const int lidx = lane & 15;                 // A-row / B-col within frag

  // per-lane fragment base pointers (byte arithmetic; 16B aligned)
  const char* Apb = (const char*)(Hp + (size_t)(row0 + wr*64 + lidx) * DD) + lgrp*16;
  const char* Bpb = (const char*)(Hp + (size_t)(jb   + wc*64 + lidx) * DD) + lgrp*16;

#define LOADF(aa, bb, ksv) do {                                                 \
    _Pragma("unroll")                                                           \
    for (int t = 0; t < 4; ++t)                                                 \
      aa[t] = *(const f16x8*)(Apb + t*16384 + (ksv)*64);                        \
    _Pragma("unroll")                                                           \
    for (int u = 0; u < 4; ++u)                                                 \
      bb[u] = *(const f16x8*)(Bpb + u*16384 + (ksv)*64);                        \
  } while (0)

#define MFMAS(aa, bb) do {                                                      \
    _Pragma("unroll")                                                           \
    for (int rt = 0; rt < 4; ++rt)                                              \
      _Pragma("unroll")                                                         \
      for (int cf = 0; cf < 4; ++cf)                                            \
        acc[rt][cf] = __builtin_amdgcn_mfma_f32_16x16x32_f16(aa[rt], bb[cf],    \
                                                             acc[rt][cf], 0, 0, 0); \
  } while (0)

  f32x4 acc[4][4] = {};
  f16x8 a0[4], b0[4], a1[4], b1[4];

  LOADF(a0, b0, 0);
  LOADF(a1, b1, 1);
#pragma unroll
  for (int ks = 0; ks < 16; ks += 2) {        // K = 512 in chunks of 32
    MFMAS(a0, b0);
    if (ks + 2 < 16) LOADF(a0, b0, ks + 2);   // issue 2 steps ahead
    MFMAS(a1, b1);
    if (ks + 3 < 16) LOADF(a1, b1, ks + 3);
  }

  // ---- fused selection epilogue: per-col top-8 over this block's 128 rows ----
  float4 sqr[4];
#pragma unroll
  for (int t = 0; t < 4; ++t)
    sqr[t] = *(const float4*)(rowsq + row0 + wr*64 + t*16 + lgrp*4);

#pragma unroll
  for (int cf = 0; cf < 4; ++cf) {
    const int jc = jb + wc*64 + cf*16 + lidx; // this lane's center column
    u64 t5[5];
#pragma unroll
    for (int s = 0; s < 5; ++s) t5[s] = ~0ull;
#pragma unroll
    for (int t = 0; t < 4; ++t) {
      const int rbase = row0 + wr*64 + t*16 + lgrp*4;
      float key;
      key = fmaf(acc[t][cf][0], KSCALE, sqr[t].x); if (rbase+0 != jc) ins5u(packkey(key, rbase+0), t5);
      key = fmaf(acc[t][cf][1], KSCALE, sqr[t].y); if (rbase+1 != jc) ins5u(packkey(key, rbase+1), t5);
      key = fmaf(acc[t][cf][2], KSCALE, sqr[t].z); if (rbase+2 != jc) ins5u(packkey(key, rbase+2), t5);
      key = fmaf(acc[t][cf][3], KSCALE, sqr[t].w); if (rbase+3 != jc) ins5u(packkey(key, rbase+3), t5);
    }
    // merge the 4 lgrp lanes sharing this col. SNAPSHOT before mutating
    // (the exchanged list must be the pre-merge value on both sides).
    u64 t8[8];
#pragma unroll
    for (int s = 0; s < 5; ++s) t8[s] = t5[s];
#pragma unroll
    for (int s = 5; s < 8; ++s) t8[s] = ~0ull;
    {
      u64 ov[5];
#pragma unroll
      for (int s = 0; s < 5; ++s) ov[s] = __shfl_xor(t5[s], 16, 64);   // d=16
#pragma unroll
      for (int s = 0; s < 5; ++s) ins8(ov[s], t8);
    }
    {
      u64 ov[8];
#pragma unroll
      for (int s = 0; s < 8; ++s) ov[s] = __shfl_xor(t8[s], 32, 64);   // d=32
#pragma unroll
      for (int s = 0; s < 8; ++s) ins8(ov[s], t8);
    }
    // wr-pair merge via LDS (the two wr waves cover different 64-row halves)
    if (wr == 1 && lane < 16) {
#pragma unroll
      for (int s = 0; s < 8; ++s) mg[(wc*64 + cf*16 + lidx)*8 + s] = t8[s];
    }
    __syncthreads();
    if (wr == 0 && lane < 16) {
      const u64* om = &mg[(wc*64 + cf*16 + lidx)*8];
#pragma unroll
      for (int s = 0; s < 8; ++s) ins8(om[s], t8);
      u64* pw = partials + ((size_t)jc * 64 + rb) * 8;
#pragma unroll
      for (int s = 0; s < 8; ++s) pw[s] = t8[s];
    }
    __syncthreads();                          // mg reused next cf
  }
#undef LOADF
#undef MFMAS
}

// ---------------------------------------------------------------------------
// Kernel 2: fold 64 partial top-8 lists per column -> cand[T][8] (sorted u64).
// One wave per column, one partial per lane.  (verbatim R8, proven)
// ---------------------------------------------------------------------------
__global__ void merge_nn8(const u64* __restrict__ parts, u64* __restrict__ cand) {
  const int j    = (int)blockIdx.x * 4 + ((int)threadIdx.x >> 6);
  const int lane = (int)threadIdx.x & 63;
  u64 tv[8];
  const u64* p0 = parts + ((size_t)j * 64 + lane) * 8;
#pragma unroll
  for (int s = 0; s < 8; ++s) tv[s] = p0[s];
#pragma unroll
  for (int d = 1; d < 64; d <<= 1) {
    u64 ov[8];
#pragma unroll
    for (int s = 0; s < 8; ++s) ov[s] = __shfl_xor(tv[s], d, 64);
#pragma unroll
    for (int s = 0; s < 8; ++s) ins8(ov[s], tv);
  }
  if (lane == 0) {
#pragma unroll
    for (int s = 0; s < 8; ++s) cand[(size_t)j*8 + s] = tv[s];
  }
}

// ---------------------------------------------------------------------------
// Kernel 3: exact fp32 refine of the 8 candidates per center -> nn[T][5].
// (verbatim R8, proven)
// ---------------------------------------------------------------------------
__global__ void refine_nn(const float* __restrict__ X, const float* __restrict__ rowsq,
                          const u64* __restrict__ cand, int* __restrict__ nn) {
  const int j    = (int)blockIdx.x * 4 + ((int)threadIdx.x >> 6);   // center
  const int lane = (int)threadIdx.x & 63;
  const float4* xj = (const float4*)(X + (size_t)j * DD);
  const float4 qa = xj[lane];
  const float4 qb = xj[lane + 64];
  u64 best[8];
#pragma unroll
  for (int s = 0; s < 8; ++s) best[s] = ~0ull;
#pragma unroll
  for (int c = 0; c < 8; ++c) {
    const int r = (int)(unsigned int)cand[(size_t)j*8 + c];
    const float4* xr_ = (const float4*)(X + (size_t)r * DD);
    const float4 a = xr_[lane];
    const float4 b = xr_[lane + 64];
    float d = a.x*qa.x + a.y*qa.y + a.z*qa.z + a.w*qa.w
            + b.x*qb.x + b.y*qb.y + b.z*qb.z + b.w*qb.w;
#pragma unroll
    for (int off = 32; off >= 1; off >>= 1) d += __shfl_xor(d, off, 64);
    const float key = fmaf(-2.f, d, rowsq[r]);
    ins8(packkey(key, r), best);              // every lane: identical result
  }
  if (lane == 0) {
#pragma unroll
    for (int s = 0; s < KNN; ++s) nn[j*KNN + s] = (int)(unsigned int)best[s];
  }
}

// ---------------------------------------------------------------------------
// Kernel 4: synthesis  out[i*4+p] = x_i + g * (x_nn - x_i)  (verbatim, proven)
// ---------------------------------------------------------------------------
__global__ void synth_kernel(const float* __restrict__ X, const int* __restrict__ nn,
                             const float* __restrict__ gaps, const int* __restrict__ choice,
                             float* __restrict__ out) {
  const float4* X4 = (const float4*)X;
  float4* O4 = (float4*)out;
  const int base = (int)blockIdx.x * 256 + (int)threadIdx.x;
#pragma unroll
  for (int it = 0; it < 8; ++it) {
    const int f    = base + it * (2048 * 256);
    const int orow = f >> 7;
    const int d4   = f & 127;
    const int i    = orow >> 2;
    const int ch   = choice[orow];
    const int nr   = nn[i * KNN + ch];
    const float g  = gaps[orow];
    const float4 xi = X4[(size_t)i  * 128 + d4];
    const float4 xn = X4[(size_t)nr * 128 + d4];
    float4 r;
    r.x = fmaf(g, xn.x - xi.x, xi.x);
    r.y = fmaf(g, xn.y - xi.y, xi.y);
    r.z = fmaf(g, xn.z - xi.z, xi.z);
    r.w = fmaf(g, xn.w - xi.w, xi.w);
    O4[(size_t)orow * 128 + d4] = r;
  }
}

// ---------------------------------------------------------------------------
// d_out (64 MB) scratch layout: H[8MB) | partials u64[8M..40M) | cand[40M..40.5M)
// — synth fully rewrites d_out last. d_ws: rowsq[32KB) + nn[160KB).
// ---------------------------------------------------------------------------
extern "C" void kernel_launch(void* const* d_in, const int* in_sizes, int n_in,
                              void* d_out, int out_size, void* d_ws, size_t ws_size,
                              hipStream_t stream) {
  const float* X      = (const float*)d_in[0];
  const float* gaps   = (const float*)d_in[1];
  const int*   choice = (const int*)  d_in[2];
  float* out = (float*)d_out;

  _Float16* Hbuf  = (_Float16*)d_out;                       // [0, 8M)
  u64*      parts = (u64*)((char*)d_out + 8388608);         // [8M, 40M)
  u64*      cand  = (u64*)((char*)d_out + 41943040);        // [40M, 40.5M)

  float* rowsq = (float*)d_ws;                              // 32 KB
  int*   nn    = (int*)((char*)d_ws + TN * 4);              // 160 KB

  prep_sq     <<<2048, 256, 0, stream>>>(X, Hbuf, rowsq);
  gemm_top8   <<<4096, 256, 0, stream>>>(Hbuf, rowsq, parts);
  merge_nn8   <<<2048, 256, 0, stream>>>(parts, cand);
  refine_nn   <<<2048, 256, 0, stream>>>(X, rowsq, cand, nn);
  synth_kernel<<<2048, 256, 0, stream>>>(X, nn, gaps, choice, out);
}